// Round 1
// baseline (501.366 us; speedup 1.0000x reference)
//
#include <hip/hip_runtime.h>
#include <hip/hip_bf16.h>

typedef __attribute__((ext_vector_type(8))) short short8;
typedef __attribute__((ext_vector_type(4))) float f32x4;

#define NROWS 65536
#define U 384
#define NTILES 1920           // 80 k-chain steps * 24 col-tiles

// ws layout (bytes)
#define SW_OFF    0
#define WFRAG_OFF 1024
#define IDX_OFF   (WFRAG_OFF + NTILES*1024)   // 1,967,104
#define MASK_OFF  (IDX_OFF + NROWS*4)         // 2,229,248

__device__ __forceinline__ unsigned short f2bf(float f){
  union { float f; unsigned u; } v; v.f = f;
  unsigned u = v.u;
  u += 0x7FFFu + ((u >> 16) & 1u);   // RNE
  return (unsigned short)(u >> 16);
}

// ---------------- prep: softmax of landmark weights ----------------
__global__ void k_prep_sw(const float* __restrict__ lw, float* __restrict__ sw){
  if (threadIdx.x == 0){
    float m = fmaxf(fmaxf(lw[0], lw[1]), fmaxf(lw[2], lw[3]));
    float e0 = expf(lw[0]-m), e1 = expf(lw[1]-m), e2 = expf(lw[2]-m), e3 = expf(lw[3]-m);
    float s = e0+e1+e2+e3;
    sw[0]=e0/s; sw[1]=e1/s; sw[2]=e2/s; sw[3]=e3/s;
  }
}

// ---------------- prep: fragment-ordered bf16 weights ----------------
// k-chain: [0,8)=W1 (lips 3, lh 2, rh 2, pose 1 ksteps, zero-padded K),
// [8,56)=W2 per branch (x12, scaled by softmax w), [56,68)=fc1, [68,80)=fc2.
__global__ void k_prep_w(const float* __restrict__ w1l, const float* __restrict__ w2l,
                         const float* __restrict__ w1lh, const float* __restrict__ w2lh,
                         const float* __restrict__ w1rh, const float* __restrict__ w2rh,
                         const float* __restrict__ w1p,  const float* __restrict__ w2p,
                         const float* __restrict__ fc1,  const float* __restrict__ fc2,
                         const float* __restrict__ sw,   unsigned short* __restrict__ wfrag){
  int gid = blockIdx.x * blockDim.x + threadIdx.x;
  if (gid >= NTILES*64) return;
  int tile = gid >> 6, lane = gid & 63;
  int kchain = tile / 24, nt = tile % 24;
  const float* src; int K = 384; float scale = 1.f; int kt;
  if (kchain < 8){
    if      (kchain < 3){ src = w1l;  K = 80; kt = kchain;     }
    else if (kchain < 5){ src = w1lh; K = 42; kt = kchain - 3; }
    else if (kchain < 7){ src = w1rh; K = 42; kt = kchain - 5; }
    else                { src = w1p;  K = 20; kt = kchain - 7; }
  } else if (kchain < 56){
    int t = kchain - 8; int br = t / 12; kt = t % 12;
    src = (br==0) ? w2l : (br==1) ? w2lh : (br==2) ? w2rh : w2p;
    scale = sw[br];
  } else if (kchain < 68){ src = fc1; kt = kchain - 56; }
  else                   { src = fc2; kt = kchain - 68; }
  int hi = lane >> 4, n = nt*16 + (lane & 15);
  short8 o;
  #pragma unroll
  for (int j = 0; j < 8; ++j){
    int k = kt*32 + hi*8 + j;
    float v = (k < K) ? scale * src[(size_t)k*U + n] : 0.f;
    o[j] = (short)f2bf(v);
  }
  *(short8*)(wfrag + ((size_t)tile << 9) + (lane << 3)) = o;
}

// ---------------- prep: pos-emb index + empty-frame masks ----------------
__global__ void k_prep_rows(const float* __restrict__ nefi,
                            const float* __restrict__ lips, const float* __restrict__ lh,
                            const float* __restrict__ rh,   const float* __restrict__ pose,
                            int* __restrict__ idxws, unsigned char* __restrict__ maskws){
  int b = blockIdx.x, s = threadIdx.x;       // 1024 x 64
  int r = b*64 + s;
  float v = nefi[r];
  float mx = v;
  #pragma unroll
  for (int off = 32; off; off >>= 1) mx = fmaxf(mx, __shfl_xor(mx, off));
  int idx = (v == -1.0f) ? 64 : (int)(floorf(v / mx) * 64.0f);
  idxws[r] = idx;
  float s0=0.f, s1=0.f, s2=0.f, s3=0.f;
  const float* p0 = lips + (size_t)r*80;
  const float* p1 = lh   + (size_t)r*42;
  const float* p2 = rh   + (size_t)r*42;
  const float* p3 = pose + (size_t)r*20;
  for (int k = 0; k < 80; ++k) s0 += p0[k];
  for (int k = 0; k < 42; ++k) s1 += p1[k];
  for (int k = 0; k < 42; ++k) s2 += p2[k];
  for (int k = 0; k < 20; ++k) s3 += p3[k];
  unsigned char mkb = (s0==0.f ? 1u:0u) | (s1==0.f ? 2u:0u) | (s2==0.f ? 4u:0u) | (s3==0.f ? 8u:0u);
  maskws[r] = mkb;
}

// ---------------- fused main kernel ----------------
// 64 rows/block, 4 waves: wave = (row-half w&1: 32 rows) x (col-half w>>1: 192 cols)
// LDS: one [64][384] bf16 buffer (row stride 768 B), XOR-swizzled byte ^= (row&7)<<4.
__device__ __forceinline__ short8 lds_rd(const char* lds, int row, int colElem){
  return *(const short8*)&lds[row*768 + ((colElem*2) ^ ((row & 7) << 4))];
}
__device__ __forceinline__ void lds_wr16(char* lds, int row, int col, unsigned short val){
  *(unsigned short*)&lds[row*768 + ((col*2) ^ ((row & 7) << 4))] = val;
}
__device__ __forceinline__ short8 bfrag(const unsigned short* wfrag, int tile, int lane){
  return *(const short8*)(wfrag + ((size_t)tile << 9) + (lane << 3));
}

__global__ __launch_bounds__(256, 2) void k_main(
    const float* __restrict__ lips, const float* __restrict__ lh,
    const float* __restrict__ rh,   const float* __restrict__ pose,
    const float* __restrict__ pos_emb,
    const unsigned short* __restrict__ wfrag,
    const int* __restrict__ idxws, const unsigned char* __restrict__ maskws,
    float* __restrict__ out)
{
  __shared__ __align__(16) char lds[64*768];
  const int tid = threadIdx.x;
  const int w = tid >> 6, lane = tid & 63;
  const int hi = lane >> 4, m = lane & 15;
  const int mrow = (w & 1) * 32;     // local row base (2 row-tiles of 16)
  const int ncol = (w >> 1) * 12;    // col-tile base (12 tiles = 192 cols)
  const int blkRow = blockIdx.x * 64;

  f32x4 yacc[24];
  #pragma unroll
  for (int i = 0; i < 24; ++i) yacc[i] = f32x4{0.f,0.f,0.f,0.f};

  const float* xs[4]  = {lips, lh, rh, pose};
  const int Ks[4]  = {80, 42, 42, 20};
  const int kcs[4] = {3, 2, 2, 1};
  const int wbs[4] = {0, 3, 5, 7};

  #pragma unroll
  for (int br = 0; br < 4; ++br){
    const float* xp = xs[br];
    const int K = Ks[br], kc = kcs[br], wb = wbs[br];

    // A fragments for this branch (guarded zero-padded loads, fp32 -> bf16)
    short8 af[2][3];
    #pragma unroll
    for (int rt = 0; rt < 2; ++rt){
      const float* rowp = xp + (size_t)(blkRow + mrow + rt*16 + m) * K;
      #pragma unroll
      for (int kt = 0; kt < 3; ++kt){
        if (kt < kc){
          short8 t;
          #pragma unroll
          for (int j = 0; j < 8; ++j){
            int k = kt*32 + hi*8 + j;
            float v = (k < K) ? rowp[k] : 0.f;
            t[j] = (short)f2bf(v);
          }
          af[rt][kt] = t;
        }
      }
    }
    // empty-frame masks for the 4 C-rows this lane writes (x2 row-tiles)
    float mk[2][4];
    #pragma unroll
    for (int rt = 0; rt < 2; ++rt)
      #pragma unroll
      for (int r = 0; r < 4; ++r)
        mk[rt][r] = ((maskws[blkRow + mrow + rt*16 + hi*4 + r] >> br) & 1) ? 0.f : 1.f;

    // stage 1: h = relu(x @ W1) * mask -> LDS (bf16)
    #pragma unroll
    for (int t = 0; t < 12; ++t){
      const int nt = ncol + t;
      #pragma unroll
      for (int rt = 0; rt < 2; ++rt){
        f32x4 acc = f32x4{0.f,0.f,0.f,0.f};
        #pragma unroll
        for (int kt = 0; kt < 3; ++kt){
          if (kt < kc){
            short8 bf = bfrag(wfrag, (wb+kt)*24 + nt, lane);
            acc = __builtin_amdgcn_mfma_f32_16x16x32_bf16(af[rt][kt], bf, acc, 0, 0, 0);
          }
        }
        #pragma unroll
        for (int r = 0; r < 4; ++r){
          const int lrow = mrow + rt*16 + hi*4 + r;
          float hv = fmaxf(acc[r], 0.f) * mk[rt][r];
          lds_wr16(lds, lrow, nt*16 + m, f2bf(hv));
        }
      }
    }
    __syncthreads();

    // stage 2: Y += h @ (w_br * W2_br)
    const int w2b = 8 + br*12;
    #pragma unroll
    for (int kt = 0; kt < 12; ++kt){
      const int ce = kt*32 + hi*8;
      short8 a0 = lds_rd(lds, mrow + m,      ce);
      short8 a1 = lds_rd(lds, mrow + 16 + m, ce);
      #pragma unroll
      for (int t = 0; t < 12; ++t){
        short8 bf = bfrag(wfrag, (w2b+kt)*24 + ncol + t, lane);
        yacc[t]      = __builtin_amdgcn_mfma_f32_16x16x32_bf16(a0, bf, yacc[t],      0, 0, 0);
        yacc[12 + t] = __builtin_amdgcn_mfma_f32_16x16x32_bf16(a1, bf, yacc[12 + t], 0, 0, 0);
      }
    }
    __syncthreads();   // before next branch overwrites h buffer
  }

  // write Y (bf16) to LDS
  #pragma unroll
  for (int t = 0; t < 12; ++t)
    #pragma unroll
    for (int rt = 0; rt < 2; ++rt)
      #pragma unroll
      for (int r = 0; r < 4; ++r)
        lds_wr16(lds, mrow + rt*16 + hi*4 + r, (ncol + t)*16 + m, f2bf(yacc[rt*12 + t][r]));
  __syncthreads();

  // stage 3: Z = Y @ fc1
  f32x4 zacc[24];
  #pragma unroll
  for (int i = 0; i < 24; ++i) zacc[i] = f32x4{0.f,0.f,0.f,0.f};
  #pragma unroll
  for (int kt = 0; kt < 12; ++kt){
    const int ce = kt*32 + hi*8;
    short8 a0 = lds_rd(lds, mrow + m,      ce);
    short8 a1 = lds_rd(lds, mrow + 16 + m, ce);
    #pragma unroll
    for (int t = 0; t < 12; ++t){
      short8 bf = bfrag(wfrag, (56+kt)*24 + ncol + t, lane);
      zacc[t]      = __builtin_amdgcn_mfma_f32_16x16x32_bf16(a0, bf, zacc[t],      0, 0, 0);
      zacc[12 + t] = __builtin_amdgcn_mfma_f32_16x16x32_bf16(a1, bf, zacc[12 + t], 0, 0, 0);
    }
  }
  __syncthreads();   // all waves done reading Y
  #pragma unroll
  for (int t = 0; t < 12; ++t)
    #pragma unroll
    for (int rt = 0; rt < 2; ++rt)
      #pragma unroll
      for (int r = 0; r < 4; ++r)
        lds_wr16(lds, mrow + rt*16 + hi*4 + r, (ncol + t)*16 + m, f2bf(fmaxf(zacc[rt*12 + t][r], 0.f)));
  __syncthreads();

  // stage 4: out = relu(Z) @ fc2 + pos_emb[idx]
  f32x4 oacc[24];
  #pragma unroll
  for (int i = 0; i < 24; ++i) oacc[i] = f32x4{0.f,0.f,0.f,0.f};
  #pragma unroll
  for (int kt = 0; kt < 12; ++kt){
    const int ce = kt*32 + hi*8;
    short8 a0 = lds_rd(lds, mrow + m,      ce);
    short8 a1 = lds_rd(lds, mrow + 16 + m, ce);
    #pragma unroll
    for (int t = 0; t < 12; ++t){
      short8 bf = bfrag(wfrag, (68+kt)*24 + ncol + t, lane);
      oacc[t]      = __builtin_amdgcn_mfma_f32_16x16x32_bf16(a0, bf, oacc[t],      0, 0, 0);
      oacc[12 + t] = __builtin_amdgcn_mfma_f32_16x16x32_bf16(a1, bf, oacc[12 + t], 0, 0, 0);
    }
  }

  // epilogue
  #pragma unroll
  for (int rt = 0; rt < 2; ++rt){
    #pragma unroll
    for (int r = 0; r < 4; ++r){
      const int grow = blkRow + mrow + rt*16 + hi*4 + r;
      const int pid = idxws[grow];
      const float* pe = pos_emb + (size_t)pid * U;
      float* op = out + (size_t)grow * U;
      #pragma unroll
      for (int t = 0; t < 12; ++t){
        const int col = (ncol + t)*16 + m;
        op[col] = oacc[rt*12 + t][r] + pe[col];
      }
    }
  }
}

extern "C" void kernel_launch(void* const* d_in, const int* in_sizes, int n_in,
                              void* d_out, int out_size, void* d_ws, size_t ws_size,
                              hipStream_t stream){
  const float* lips = (const float*)d_in[0];
  const float* lh   = (const float*)d_in[1];
  const float* rh   = (const float*)d_in[2];
  const float* pose = (const float*)d_in[3];
  const float* nefi = (const float*)d_in[4];
  const float* w1l  = (const float*)d_in[5];
  const float* w2l  = (const float*)d_in[6];
  const float* w1lh = (const float*)d_in[7];
  const float* w2lh = (const float*)d_in[8];
  const float* w1rh = (const float*)d_in[9];
  const float* w2rh = (const float*)d_in[10];
  const float* w1p  = (const float*)d_in[11];
  const float* w2p  = (const float*)d_in[12];
  const float* lw   = (const float*)d_in[13];
  const float* fc1  = (const float*)d_in[14];
  const float* fc2  = (const float*)d_in[15];
  const float* pemb = (const float*)d_in[16];
  float* out = (float*)d_out;
  char* ws = (char*)d_ws;
  float* sw = (float*)(ws + SW_OFF);
  unsigned short* wfrag = (unsigned short*)(ws + WFRAG_OFF);
  int* idxws = (int*)(ws + IDX_OFF);
  unsigned char* maskws = (unsigned char*)(ws + MASK_OFF);

  k_prep_sw<<<1, 64, 0, stream>>>(lw, sw);
  k_prep_w<<<(NTILES*64)/256, 256, 0, stream>>>(w1l, w2l, w1lh, w2lh, w1rh, w2rh,
                                                w1p, w2p, fc1, fc2, sw, wfrag);
  k_prep_rows<<<1024, 64, 0, stream>>>(nefi, lips, lh, rh, pose, idxws, maskws);
  k_main<<<1024, 256, 0, stream>>>(lips, lh, rh, pose, pemb, wfrag, idxws, maskws, out);
}

// Round 3
// 489.940 us; speedup vs baseline: 1.0233x; 1.0233x over previous
//
#include <hip/hip_runtime.h>
#include <hip/hip_bf16.h>

typedef __attribute__((ext_vector_type(8))) short short8;
typedef __attribute__((ext_vector_type(4))) float f32x4;

#define NROWS 65536
#define U 384
#define NTILES 1920           // 80 k-chain steps * 24 col-tiles

// ws layout (bytes)
#define SW_OFF    0
#define WFRAG_OFF 1024
#define IDX_OFF   (WFRAG_OFF + NTILES*1024)   // 1,967,104

__device__ __forceinline__ unsigned short f2bf(float f){
  union { float f; unsigned u; } v; v.f = f;
  unsigned u = v.u;
  u += 0x7FFFu + ((u >> 16) & 1u);   // RNE
  return (unsigned short)(u >> 16);
}

// ---------------- prep: softmax of landmark weights ----------------
__global__ void k_prep_sw(const float* __restrict__ lw, float* __restrict__ sw){
  if (threadIdx.x == 0){
    float m = fmaxf(fmaxf(lw[0], lw[1]), fmaxf(lw[2], lw[3]));
    float e0 = expf(lw[0]-m), e1 = expf(lw[1]-m), e2 = expf(lw[2]-m), e3 = expf(lw[3]-m);
    float s = e0+e1+e2+e3;
    sw[0]=e0/s; sw[1]=e1/s; sw[2]=e2/s; sw[3]=e3/s;
  }
}

// ---------------- prep: fragment-ordered bf16 weights ----------------
// k-chain: [0,8)=W1 (lips 3, lh 2, rh 2, pose 1 ksteps, zero-padded K),
// [8,56)=W2 per branch (x12, scaled by softmax w), [56,68)=fc1, [68,80)=fc2.
__global__ void k_prep_w(const float* __restrict__ w1l, const float* __restrict__ w2l,
                         const float* __restrict__ w1lh, const float* __restrict__ w2lh,
                         const float* __restrict__ w1rh, const float* __restrict__ w2rh,
                         const float* __restrict__ w1p,  const float* __restrict__ w2p,
                         const float* __restrict__ fc1,  const float* __restrict__ fc2,
                         const float* __restrict__ sw,   unsigned short* __restrict__ wfrag){
  int gid = blockIdx.x * blockDim.x + threadIdx.x;
  if (gid >= NTILES*64) return;
  int tile = gid >> 6, lane = gid & 63;
  int kchain = tile / 24, nt = tile % 24;
  const float* src; int K = 384; float scale = 1.f; int kt;
  if (kchain < 8){
    if      (kchain < 3){ src = w1l;  K = 80; kt = kchain;     }
    else if (kchain < 5){ src = w1lh; K = 42; kt = kchain - 3; }
    else if (kchain < 7){ src = w1rh; K = 42; kt = kchain - 5; }
    else                { src = w1p;  K = 20; kt = kchain - 7; }
  } else if (kchain < 56){
    int t = kchain - 8; int br = t / 12; kt = t % 12;
    src = (br==0) ? w2l : (br==1) ? w2lh : (br==2) ? w2rh : w2p;
    scale = sw[br];
  } else if (kchain < 68){ src = fc1; kt = kchain - 56; }
  else                   { src = fc2; kt = kchain - 68; }
  int hi = lane >> 4, n = nt*16 + (lane & 15);
  short8 o;
  #pragma unroll
  for (int j = 0; j < 8; ++j){
    int k = kt*32 + hi*8 + j;
    float v = (k < K) ? scale * src[(size_t)k*U + n] : 0.f;
    o[j] = (short)f2bf(v);
  }
  *(short8*)(wfrag + ((size_t)tile << 9) + (lane << 3)) = o;
}

// ---------------- prep: pos-emb index only (masks are computed in k_main) ----
__global__ void k_prep_idx(const float* __restrict__ nefi, int* __restrict__ idxws){
  int b = blockIdx.x, s = threadIdx.x;       // 1024 x 64
  int r = b*64 + s;
  float v = nefi[r];
  float mx = v;
  #pragma unroll
  for (int off = 32; off; off >>= 1) mx = fmaxf(mx, __shfl_xor(mx, off));
  idxws[r] = (v == -1.0f) ? 64 : (int)(floorf(v / mx) * 64.0f);
}

// ---------------- fused main kernel ----------------
// 128 rows/block, 8 waves: wave = (rowg w&1: 64 rows = 4 row-tiles) x
// (colg w>>1: 96 cols = 6 col-tiles). LDS: one [128][384] bf16 buffer
// (row stride 768 B), XOR-swizzled byte ^= (row&7)<<4.
__device__ __forceinline__ short8 lds_rd(const char* lds, int row, int colElem){
  return *(const short8*)&lds[row*768 + ((colElem*2) ^ ((row & 7) << 4))];
}
__device__ __forceinline__ void lds_wr16(char* lds, int row, int col, unsigned short val){
  *(unsigned short*)&lds[row*768 + ((col*2) ^ ((row & 7) << 4))] = val;
}
__device__ __forceinline__ short8 bfrag(const unsigned short* wfrag, int tile, int lane){
  return *(const short8*)(wfrag + ((size_t)tile << 9) + (lane << 3));
}

__global__ __launch_bounds__(512, 1) void k_main(
    const float* __restrict__ lips, const float* __restrict__ lh,
    const float* __restrict__ rh,   const float* __restrict__ pose,
    const float* __restrict__ pos_emb,
    const unsigned short* __restrict__ wfrag,
    const int* __restrict__ idxws,
    float* __restrict__ out)
{
  __shared__ __align__(16) char lds[128*768];
  const int tid = threadIdx.x;
  const int w = tid >> 6, lane = tid & 63;
  const int hi = lane >> 4, m = lane & 15;
  const int mrow = (w & 1) * 64;     // local row base (4 row-tiles of 16)
  const int nct  = (w >> 1) * 6;     // col-tile base (6 tiles = 96 cols)
  const int blkRow = blockIdx.x * 128;

  f32x4 yacc[24];                    // [rt][t] = rt*6+t
  #pragma unroll
  for (int i = 0; i < 24; ++i) yacc[i] = f32x4{0.f,0.f,0.f,0.f};

  const float* xs[4]  = {lips, lh, rh, pose};
  const int Ks[4]  = {80, 42, 42, 20};
  const int kcs[4] = {3, 2, 2, 1};
  const int wbs[4] = {0, 3, 5, 7};

  #pragma unroll
  for (int br = 0; br < 4; ++br){
    const float* xp = xs[br];
    const int K = Ks[br], kc = kcs[br], wb = wbs[br];

    // A fragments + in-flight row sums (empty-frame mask, fp32-exact like ref)
    short8 af[4][3];
    float mk[4][4];
    #pragma unroll
    for (int rt = 0; rt < 4; ++rt){
      const float* rowp = xp + (size_t)(blkRow + mrow + rt*16 + m) * K;
      float s = 0.f;
      #pragma unroll
      for (int kt = 0; kt < 3; ++kt){
        if (kt < kc){
          short8 t8;
          #pragma unroll
          for (int j = 0; j < 8; ++j){
            int k = kt*32 + hi*8 + j;
            float v = (k < K) ? rowp[k] : 0.f;
            s += v;
            t8[j] = (short)f2bf(v);
          }
          af[rt][kt] = t8;
        }
      }
      s += __shfl_xor(s, 16);
      s += __shfl_xor(s, 32);        // now full row-sum for row (rt, m) in all 4 hi-lanes
      #pragma unroll
      for (int r = 0; r < 4; ++r)
        mk[rt][r] = (__shfl(s, hi*4 + r) == 0.f) ? 0.f : 1.f;
    }

    // stage 1: h = relu(x @ W1) * mask -> LDS (bf16)
    #pragma unroll
    for (int t = 0; t < 6; ++t){
      const int nt = nct + t;
      #pragma unroll
      for (int rt = 0; rt < 4; ++rt){
        f32x4 acc = f32x4{0.f,0.f,0.f,0.f};
        #pragma unroll
        for (int kt = 0; kt < 3; ++kt){
          if (kt < kc){
            short8 bf = bfrag(wfrag, (wb+kt)*24 + nt, lane);
            acc = __builtin_amdgcn_mfma_f32_16x16x32_bf16(af[rt][kt], bf, acc, 0, 0, 0);
          }
        }
        #pragma unroll
        for (int r = 0; r < 4; ++r){
          const int lrow = mrow + rt*16 + hi*4 + r;
          lds_wr16(lds, lrow, nt*16 + m, f2bf(fmaxf(acc[r], 0.f) * mk[rt][r]));
        }
      }
    }
    __syncthreads();

    // stage 2: Y += h @ (w_br * W2_br)
    const int w2b = 8 + br*12;
    #pragma unroll
    for (int kt = 0; kt < 12; ++kt){
      const int ce = kt*32 + hi*8;
      short8 a0 = lds_rd(lds, mrow + m,      ce);
      short8 a1 = lds_rd(lds, mrow + 16 + m, ce);
      short8 a2 = lds_rd(lds, mrow + 32 + m, ce);
      short8 a3 = lds_rd(lds, mrow + 48 + m, ce);
      #pragma unroll
      for (int t = 0; t < 6; ++t){
        short8 bf = bfrag(wfrag, (w2b+kt)*24 + nct + t, lane);
        yacc[t]      = __builtin_amdgcn_mfma_f32_16x16x32_bf16(a0, bf, yacc[t],      0, 0, 0);
        yacc[6 + t]  = __builtin_amdgcn_mfma_f32_16x16x32_bf16(a1, bf, yacc[6 + t],  0, 0, 0);
        yacc[12 + t] = __builtin_amdgcn_mfma_f32_16x16x32_bf16(a2, bf, yacc[12 + t], 0, 0, 0);
        yacc[18 + t] = __builtin_amdgcn_mfma_f32_16x16x32_bf16(a3, bf, yacc[18 + t], 0, 0, 0);
      }
    }
    __syncthreads();   // before next branch overwrites h buffer
  }

  // write Y (bf16) to LDS
  #pragma unroll
  for (int t = 0; t < 6; ++t)
    #pragma unroll
    for (int rt = 0; rt < 4; ++rt)
      #pragma unroll
      for (int r = 0; r < 4; ++r)
        lds_wr16(lds, mrow + rt*16 + hi*4 + r, (nct + t)*16 + m, f2bf(yacc[rt*6 + t][r]));
  __syncthreads();

  // stage 3: Z = Y @ fc1
  f32x4 zacc[24];
  #pragma unroll
  for (int i = 0; i < 24; ++i) zacc[i] = f32x4{0.f,0.f,0.f,0.f};
  #pragma unroll
  for (int kt = 0; kt < 12; ++kt){
    const int ce = kt*32 + hi*8;
    short8 a0 = lds_rd(lds, mrow + m,      ce);
    short8 a1 = lds_rd(lds, mrow + 16 + m, ce);
    short8 a2 = lds_rd(lds, mrow + 32 + m, ce);
    short8 a3 = lds_rd(lds, mrow + 48 + m, ce);
    #pragma unroll
    for (int t = 0; t < 6; ++t){
      short8 bf = bfrag(wfrag, (56+kt)*24 + nct + t, lane);
      zacc[t]      = __builtin_amdgcn_mfma_f32_16x16x32_bf16(a0, bf, zacc[t],      0, 0, 0);
      zacc[6 + t]  = __builtin_amdgcn_mfma_f32_16x16x32_bf16(a1, bf, zacc[6 + t],  0, 0, 0);
      zacc[12 + t] = __builtin_amdgcn_mfma_f32_16x16x32_bf16(a2, bf, zacc[12 + t], 0, 0, 0);
      zacc[18 + t] = __builtin_amdgcn_mfma_f32_16x16x32_bf16(a3, bf, zacc[18 + t], 0, 0, 0);
    }
  }
  __syncthreads();   // all waves done reading Y
  #pragma unroll
  for (int t = 0; t < 6; ++t)
    #pragma unroll
    for (int rt = 0; rt < 4; ++rt)
      #pragma unroll
      for (int r = 0; r < 4; ++r)
        lds_wr16(lds, mrow + rt*16 + hi*4 + r, (nct + t)*16 + m, f2bf(fmaxf(zacc[rt*6 + t][r], 0.f)));
  __syncthreads();

  // stage 4: out = relu(Z) @ fc2 + pos_emb[idx]
  f32x4 oacc[24];
  #pragma unroll
  for (int i = 0; i < 24; ++i) oacc[i] = f32x4{0.f,0.f,0.f,0.f};
  #pragma unroll
  for (int kt = 0; kt < 12; ++kt){
    const int ce = kt*32 + hi*8;
    short8 a0 = lds_rd(lds, mrow + m,      ce);
    short8 a1 = lds_rd(lds, mrow + 16 + m, ce);
    short8 a2 = lds_rd(lds, mrow + 32 + m, ce);
    short8 a3 = lds_rd(lds, mrow + 48 + m, ce);
    #pragma unroll
    for (int t = 0; t < 6; ++t){
      short8 bf = bfrag(wfrag, (68+kt)*24 + nct + t, lane);
      oacc[t]      = __builtin_amdgcn_mfma_f32_16x16x32_bf16(a0, bf, oacc[t],      0, 0, 0);
      oacc[6 + t]  = __builtin_amdgcn_mfma_f32_16x16x32_bf16(a1, bf, oacc[6 + t],  0, 0, 0);
      oacc[12 + t] = __builtin_amdgcn_mfma_f32_16x16x32_bf16(a2, bf, oacc[12 + t], 0, 0, 0);
      oacc[18 + t] = __builtin_amdgcn_mfma_f32_16x16x32_bf16(a3, bf, oacc[18 + t], 0, 0, 0);
    }
  }

  // epilogue
  #pragma unroll
  for (int rt = 0; rt < 4; ++rt){
    #pragma unroll
    for (int r = 0; r < 4; ++r){
      const int grow = blkRow + mrow + rt*16 + hi*4 + r;
      const int pid = idxws[grow];
      const float* pe = pos_emb + (size_t)pid * U;
      float* op = out + (size_t)grow * U;
      #pragma unroll
      for (int t = 0; t < 6; ++t){
        const int col = (nct + t)*16 + m;
        op[col] = oacc[rt*6 + t][r] + pe[col];
      }
    }
  }
}

extern "C" void kernel_launch(void* const* d_in, const int* in_sizes, int n_in,
                              void* d_out, int out_size, void* d_ws, size_t ws_size,
                              hipStream_t stream){
  const float* lips = (const float*)d_in[0];
  const float* lh   = (const float*)d_in[1];
  const float* rh   = (const float*)d_in[2];
  const float* pose = (const float*)d_in[3];
  const float* nefi = (const float*)d_in[4];
  const float* w1l  = (const float*)d_in[5];
  const float* w2l  = (const float*)d_in[6];
  const float* w1lh = (const float*)d_in[7];
  const float* w2lh = (const float*)d_in[8];
  const float* w1rh = (const float*)d_in[9];
  const float* w2rh = (const float*)d_in[10];
  const float* w1p  = (const float*)d_in[11];
  const float* w2p  = (const float*)d_in[12];
  const float* lw   = (const float*)d_in[13];
  const float* fc1  = (const float*)d_in[14];
  const float* fc2  = (const float*)d_in[15];
  const float* pemb = (const float*)d_in[16];
  float* out = (float*)d_out;
  char* ws = (char*)d_ws;
  float* sw = (float*)(ws + SW_OFF);
  unsigned short* wfrag = (unsigned short*)(ws + WFRAG_OFF);
  int* idxws = (int*)(ws + IDX_OFF);

  k_prep_sw<<<1, 64, 0, stream>>>(lw, sw);
  k_prep_w<<<(NTILES*64)/256, 256, 0, stream>>>(w1l, w2l, w1lh, w2lh, w1rh, w2rh,
                                                w1p, w2p, fc1, fc2, sw, wfrag);
  k_prep_idx<<<1024, 64, 0, stream>>>(nefi, idxws);
  k_main<<<512, 512, 0, stream>>>(lips, lh, rh, pose, pemb, wfrag, idxws, out);
}

// Round 4
// 439.402 us; speedup vs baseline: 1.1410x; 1.1150x over previous
//
#include <hip/hip_runtime.h>
#include <hip/hip_bf16.h>

typedef __attribute__((ext_vector_type(8))) short short8;
typedef __attribute__((ext_vector_type(4))) float f32x4;

#define NROWS 65536
#define U 384
#define NTILES 1920           // 80 k-chain steps * 24 col-tiles

// ws layout (bytes)
#define SW_OFF    0
#define WFRAG_OFF 1024
#define IDX_OFF   (WFRAG_OFF + NTILES*1024)   // 1,967,104

__device__ __forceinline__ unsigned short f2bf(float f){
  union { float f; unsigned u; } v; v.f = f;
  unsigned u = v.u;
  u += 0x7FFFu + ((u >> 16) & 1u);   // RNE
  return (unsigned short)(u >> 16);
}

// ---------------- prep: softmax of landmark weights ----------------
__global__ void k_prep_sw(const float* __restrict__ lw, float* __restrict__ sw){
  if (threadIdx.x == 0){
    float m = fmaxf(fmaxf(lw[0], lw[1]), fmaxf(lw[2], lw[3]));
    float e0 = expf(lw[0]-m), e1 = expf(lw[1]-m), e2 = expf(lw[2]-m), e3 = expf(lw[3]-m);
    float s = e0+e1+e2+e3;
    sw[0]=e0/s; sw[1]=e1/s; sw[2]=e2/s; sw[3]=e3/s;
  }
}

// ---------------- prep: fragment-ordered bf16 weights (slab version) --------
// One block per k-chain step (grid=80). Coalesced slab load -> LDS,
// then coalesced 16-B fragment writes.
// k-chain: [0,8)=W1 (lips 3, lh 2, rh 2, pose 1 ksteps, zero-padded K),
// [8,56)=W2 per branch (x12, scaled by softmax w), [56,68)=fc1, [68,80)=fc2.
__global__ void k_prep_w(const float* __restrict__ w1l, const float* __restrict__ w2l,
                         const float* __restrict__ w1lh, const float* __restrict__ w2lh,
                         const float* __restrict__ w1rh, const float* __restrict__ w2rh,
                         const float* __restrict__ w1p,  const float* __restrict__ w2p,
                         const float* __restrict__ fc1,  const float* __restrict__ fc2,
                         const float* __restrict__ sw,   unsigned short* __restrict__ wfrag){
  __shared__ float slab[32*384];
  const int kchain = blockIdx.x, tid = threadIdx.x;
  const float* src; int K = 384; float scale = 1.f; int kt;
  if (kchain < 8){
    if      (kchain < 3){ src = w1l;  K = 80; kt = kchain;     }
    else if (kchain < 5){ src = w1lh; K = 42; kt = kchain - 3; }
    else if (kchain < 7){ src = w1rh; K = 42; kt = kchain - 5; }
    else                { src = w1p;  K = 20; kt = kchain - 7; }
  } else if (kchain < 56){
    int t = kchain - 8; int br = t / 12; kt = t % 12;
    src = (br==0) ? w2l : (br==1) ? w2lh : (br==2) ? w2rh : w2p;
    scale = sw[br];
  } else if (kchain < 68){ src = fc1; kt = kchain - 56; }
  else                   { src = fc2; kt = kchain - 68; }

  for (int idx = tid; idx < 32*384; idx += 256){
    int kk = idx / 384, n = idx - kk*384;
    int k = kt*32 + kk;
    slab[idx] = (k < K) ? scale * src[(size_t)k*U + n] : 0.f;
  }
  __syncthreads();
  for (int p = tid; p < 24*64; p += 256){
    int nt = p >> 6, lane = p & 63;
    int hi = lane >> 4, m = lane & 15;
    short8 o;
    #pragma unroll
    for (int j = 0; j < 8; ++j)
      o[j] = (short)f2bf(slab[(hi*8 + j)*384 + nt*16 + m]);
    *(short8*)(wfrag + ((size_t)(kchain*24 + nt) << 9) + (lane << 3)) = o;
  }
}

// ---------------- prep: pos-emb index only (masks are computed in k_main) ----
__global__ void k_prep_idx(const float* __restrict__ nefi, int* __restrict__ idxws){
  int b = blockIdx.x, s = threadIdx.x;       // 1024 x 64
  int r = b*64 + s;
  float v = nefi[r];
  float mx = v;
  #pragma unroll
  for (int off = 32; off; off >>= 1) mx = fmaxf(mx, __shfl_xor(mx, off));
  idxws[r] = (v == -1.0f) ? 64 : (int)(floorf(v / mx) * 64.0f);
}

// ---------------- fused main kernel ----------------
// 64 rows/block, 8 waves: wave = (rowg w>>2: 32 rows = 2 row-tiles) x
// (colg w&3: 96 cols = 6 col-tiles). LDS: one [64][384] bf16 buffer
// (row stride 768 B), XOR-swizzled byte ^= (row&7)<<4.
// acc = 12 f32x4 (48 VGPR) -> leaves room for register-double-buffered B
// fragments (2x6 short8 = 48 VGPR), prefetched one k-step ahead.
__device__ __forceinline__ short8 lds_rd(const char* lds, int row, int colElem){
  return *(const short8*)&lds[row*768 + ((colElem*2) ^ ((row & 7) << 4))];
}
__device__ __forceinline__ void lds_wr16(char* lds, int row, int col, unsigned short val){
  *(unsigned short*)&lds[row*768 + ((col*2) ^ ((row & 7) << 4))] = val;
}
__device__ __forceinline__ short8 bfrag(const unsigned short* wfrag, int tile, int lane){
  return *(const short8*)(wfrag + ((size_t)tile << 9) + (lane << 3));
}

// 384-deep GEMM stage: ACC[12] += A(lds rows mrow..mrow+31) @ B(kchain KBASE..KBASE+11)
#define GEMM384(ACC, KBASE) do {                                                         \
  short8 bb[2][6];                                                                       \
  _Pragma("unroll")                                                                      \
  for (int t = 0; t < 6; ++t) bb[0][t] = bfrag(wfrag, (KBASE)*24 + nct + t, lane);       \
  _Pragma("unroll")                                                                      \
  for (int kt = 0; kt < 12; ++kt){                                                       \
    if (kt < 11){                                                                        \
      _Pragma("unroll")                                                                  \
      for (int t = 0; t < 6; ++t)                                                        \
        bb[(kt+1)&1][t] = bfrag(wfrag, (KBASE + kt + 1)*24 + nct + t, lane);             \
    }                                                                                    \
    const int ce = kt*32 + hi*8;                                                         \
    short8 a0 = lds_rd(lds, mrow + m,      ce);                                          \
    short8 a1 = lds_rd(lds, mrow + 16 + m, ce);                                          \
    _Pragma("unroll")                                                                    \
    for (int t = 0; t < 6; ++t){                                                         \
      ACC[t]     = __builtin_amdgcn_mfma_f32_16x16x32_bf16(a0, bb[kt&1][t], ACC[t],     0, 0, 0); \
      ACC[6 + t] = __builtin_amdgcn_mfma_f32_16x16x32_bf16(a1, bb[kt&1][t], ACC[6 + t], 0, 0, 0); \
    }                                                                                    \
  }                                                                                      \
} while(0)

__global__ __launch_bounds__(512, 4) void k_main(
    const float* __restrict__ lips, const float* __restrict__ lh,
    const float* __restrict__ rh,   const float* __restrict__ pose,
    const float* __restrict__ pos_emb,
    const unsigned short* __restrict__ wfrag,
    const int* __restrict__ idxws,
    float* __restrict__ out)
{
  __shared__ __align__(16) char lds[64*768];
  const int tid = threadIdx.x;
  const int w = tid >> 6, lane = tid & 63;
  const int hi = lane >> 4, m = lane & 15;
  const int mrow = (w >> 2) * 32;    // local row base (2 row-tiles of 16)
  const int nct  = (w & 3) * 6;      // col-tile base (6 tiles = 96 cols)
  const int blkRow = blockIdx.x * 64;

  f32x4 yacc[12];                    // [rt*6+t], rt 0..1, t 0..5
  #pragma unroll
  for (int i = 0; i < 12; ++i) yacc[i] = f32x4{0.f,0.f,0.f,0.f};

  const float* xs[4]  = {lips, lh, rh, pose};
  const int Ks[4]  = {80, 42, 42, 20};
  const int kcs[4] = {3, 2, 2, 1};
  const int wbs[4] = {0, 3, 5, 7};

  #pragma unroll
  for (int br = 0; br < 4; ++br){
    const float* xp = xs[br];
    const int K = Ks[br], kc = kcs[br], wb = wbs[br];

    // A fragments + in-flight row sums (empty-frame mask, fp32-exact like ref)
    short8 af[2][3];
    float mk[2][4];
    #pragma unroll
    for (int rt = 0; rt < 2; ++rt){
      const float* rowp = xp + (size_t)(blkRow + mrow + rt*16 + m) * K;
      float s = 0.f;
      #pragma unroll
      for (int kt = 0; kt < 3; ++kt){
        if (kt < kc){
          short8 t8;
          #pragma unroll
          for (int j = 0; j < 8; ++j){
            int k = kt*32 + hi*8 + j;
            float v = (k < K) ? rowp[k] : 0.f;
            s += v;
            t8[j] = (short)f2bf(v);
          }
          af[rt][kt] = t8;
        }
      }
      s += __shfl_xor(s, 16);
      s += __shfl_xor(s, 32);        // full row-sum for row (rt, m) in all 4 hi-lanes
      #pragma unroll
      for (int r = 0; r < 4; ++r)
        mk[rt][r] = (__shfl(s, hi*4 + r) == 0.f) ? 0.f : 1.f;
    }

    // stage 1: h = relu(x @ W1) * mask -> LDS (bf16), B prefetched across t
    {
      short8 bs[2][3];
      #pragma unroll
      for (int kt = 0; kt < 3; ++kt)
        if (kt < kc) bs[0][kt] = bfrag(wfrag, (wb+kt)*24 + nct, lane);
      #pragma unroll
      for (int t = 0; t < 6; ++t){
        if (t < 5){
          #pragma unroll
          for (int kt = 0; kt < 3; ++kt)
            if (kt < kc) bs[(t+1)&1][kt] = bfrag(wfrag, (wb+kt)*24 + nct + t + 1, lane);
        }
        #pragma unroll
        for (int rt = 0; rt < 2; ++rt){
          f32x4 acc = f32x4{0.f,0.f,0.f,0.f};
          #pragma unroll
          for (int kt = 0; kt < 3; ++kt)
            if (kt < kc)
              acc = __builtin_amdgcn_mfma_f32_16x16x32_bf16(af[rt][kt], bs[t&1][kt], acc, 0, 0, 0);
          #pragma unroll
          for (int r = 0; r < 4; ++r){
            const int lrow = mrow + rt*16 + hi*4 + r;
            lds_wr16(lds, lrow, (nct + t)*16 + m, f2bf(fmaxf(acc[r], 0.f) * mk[rt][r]));
          }
        }
      }
    }
    __syncthreads();

    // stage 2: Y += h @ (w_br * W2_br)
    GEMM384(yacc, 8 + br*12);
    __syncthreads();   // before next branch overwrites h buffer
  }

  // write Y (bf16) to LDS
  #pragma unroll
  for (int t = 0; t < 6; ++t)
    #pragma unroll
    for (int rt = 0; rt < 2; ++rt)
      #pragma unroll
      for (int r = 0; r < 4; ++r)
        lds_wr16(lds, mrow + rt*16 + hi*4 + r, (nct + t)*16 + m, f2bf(yacc[rt*6 + t][r]));
  __syncthreads();

  // stage 3: Z = Y @ fc1
  f32x4 zacc[12];
  #pragma unroll
  for (int i = 0; i < 12; ++i) zacc[i] = f32x4{0.f,0.f,0.f,0.f};
  GEMM384(zacc, 56);
  __syncthreads();   // all waves done reading Y
  #pragma unroll
  for (int t = 0; t < 6; ++t)
    #pragma unroll
    for (int rt = 0; rt < 2; ++rt)
      #pragma unroll
      for (int r = 0; r < 4; ++r)
        lds_wr16(lds, mrow + rt*16 + hi*4 + r, (nct + t)*16 + m, f2bf(fmaxf(zacc[rt*6 + t][r], 0.f)));
  __syncthreads();

  // stage 4: out = relu(Z) @ fc2 + pos_emb[idx]
  f32x4 oacc[12];
  #pragma unroll
  for (int i = 0; i < 12; ++i) oacc[i] = f32x4{0.f,0.f,0.f,0.f};
  GEMM384(oacc, 68);

  // epilogue
  #pragma unroll
  for (int rt = 0; rt < 2; ++rt){
    #pragma unroll
    for (int r = 0; r < 4; ++r){
      const int grow = blkRow + mrow + rt*16 + hi*4 + r;
      const int pid = idxws[grow];
      const float* pe = pos_emb + (size_t)pid * U;
      float* op = out + (size_t)grow * U;
      #pragma unroll
      for (int t = 0; t < 6; ++t){
        const int col = (nct + t)*16 + m;
        op[col] = oacc[rt*6 + t][r] + pe[col];
      }
    }
  }
}

extern "C" void kernel_launch(void* const* d_in, const int* in_sizes, int n_in,
                              void* d_out, int out_size, void* d_ws, size_t ws_size,
                              hipStream_t stream){
  const float* lips = (const float*)d_in[0];
  const float* lh   = (const float*)d_in[1];
  const float* rh   = (const float*)d_in[2];
  const float* pose = (const float*)d_in[3];
  const float* nefi = (const float*)d_in[4];
  const float* w1l  = (const float*)d_in[5];
  const float* w2l  = (const float*)d_in[6];
  const float* w1lh = (const float*)d_in[7];
  const float* w2lh = (const float*)d_in[8];
  const float* w1rh = (const float*)d_in[9];
  const float* w2rh = (const float*)d_in[10];
  const float* w1p  = (const float*)d_in[11];
  const float* w2p  = (const float*)d_in[12];
  const float* lw   = (const float*)d_in[13];
  const float* fc1  = (const float*)d_in[14];
  const float* fc2  = (const float*)d_in[15];
  const float* pemb = (const float*)d_in[16];
  float* out = (float*)d_out;
  char* ws = (char*)d_ws;
  float* sw = (float*)(ws + SW_OFF);
  unsigned short* wfrag = (unsigned short*)(ws + WFRAG_OFF);
  int* idxws = (int*)(ws + IDX_OFF);

  k_prep_sw<<<1, 64, 0, stream>>>(lw, sw);
  k_prep_w<<<80, 256, 0, stream>>>(w1l, w2l, w1lh, w2lh, w1rh, w2rh,
                                   w1p, w2p, fc1, fc2, sw, wfrag);
  k_prep_idx<<<1024, 64, 0, stream>>>(nefi, idxws);
  k_main<<<1024, 512, 0, stream>>>(lips, lh, rh, pose, pemb, wfrag, idxws, out);
}

// Round 5
// 417.389 us; speedup vs baseline: 1.2012x; 1.0527x over previous
//
#include <hip/hip_runtime.h>
#include <hip/hip_bf16.h>

typedef __attribute__((ext_vector_type(8))) short short8;
typedef __attribute__((ext_vector_type(4))) float f32x4;

#define NROWS 65536
#define U 384
#define NTILES 1920            // 80 k-chain steps * 24 col-tiles
#define WFRAG_OFF 0
#define IDX_OFF (NTILES*1024)  // 1,966,080 bytes

#define ACT_BYTES (128*768)    // 98304: [128][384] bf16, swizzled
#define BOFF ACT_BYTES         // two B k-step buffers of 24576 B
#define LDS_TOTAL (ACT_BYTES + 2*24576)   // 147456

#define WAITVM(N) asm volatile("s_waitcnt vmcnt(" #N ")" ::: "memory")

__device__ __forceinline__ unsigned short f2bf(float f){
  union { float f; unsigned u; } v; v.f = f;
  unsigned u = v.u;
  u += 0x7FFFu + ((u >> 16) & 1u);   // RNE
  return (unsigned short)(u >> 16);
}

// ---------------- prep: fragment-ordered bf16 weights (slab version) --------
// One block per k-chain step (grid=80). softmax(lw) computed in-kernel.
// k-chain: [0,8)=W1 (lips 3, lh 2, rh 2, pose 1, zero-padded K),
// [8,56)=W2 per branch (x12, scaled by softmax w), [56,68)=fc1, [68,80)=fc2.
__global__ void k_prep_w(const float* __restrict__ w1l, const float* __restrict__ w2l,
                         const float* __restrict__ w1lh, const float* __restrict__ w2lh,
                         const float* __restrict__ w1rh, const float* __restrict__ w2rh,
                         const float* __restrict__ w1p,  const float* __restrict__ w2p,
                         const float* __restrict__ fc1,  const float* __restrict__ fc2,
                         const float* __restrict__ lw,   unsigned short* __restrict__ wfrag){
  __shared__ float slab[32*384];
  const int kchain = blockIdx.x, tid = threadIdx.x;
  // softmax of landmark weights (tiny, every thread)
  float m0 = fmaxf(fmaxf(lw[0], lw[1]), fmaxf(lw[2], lw[3]));
  float e0 = expf(lw[0]-m0), e1 = expf(lw[1]-m0), e2 = expf(lw[2]-m0), e3 = expf(lw[3]-m0);
  float es = e0+e1+e2+e3;
  float swv[4] = {e0/es, e1/es, e2/es, e3/es};

  const float* src; int K = 384; float scale = 1.f; int kt;
  if (kchain < 8){
    if      (kchain < 3){ src = w1l;  K = 80; kt = kchain;     }
    else if (kchain < 5){ src = w1lh; K = 42; kt = kchain - 3; }
    else if (kchain < 7){ src = w1rh; K = 42; kt = kchain - 5; }
    else                { src = w1p;  K = 20; kt = kchain - 7; }
  } else if (kchain < 56){
    int t = kchain - 8; int br = t / 12; kt = t % 12;
    src = (br==0) ? w2l : (br==1) ? w2lh : (br==2) ? w2rh : w2p;
    scale = swv[br];
  } else if (kchain < 68){ src = fc1; kt = kchain - 56; }
  else                   { src = fc2; kt = kchain - 68; }

  for (int idx = tid; idx < 32*384; idx += 256){
    int kk = idx / 384, n = idx - kk*384;
    int k = kt*32 + kk;
    slab[idx] = (k < K) ? scale * src[(size_t)k*U + n] : 0.f;
  }
  __syncthreads();
  for (int p = tid; p < 24*64; p += 256){
    int nt = p >> 6, lane = p & 63;
    int hi = lane >> 4, m = lane & 15;
    short8 o;
    #pragma unroll
    for (int j = 0; j < 8; ++j)
      o[j] = (short)f2bf(slab[(hi*8 + j)*384 + nt*16 + m]);
    *(short8*)(wfrag + ((size_t)(kchain*24 + nt) << 9) + (lane << 3)) = o;
  }
}

// ---------------- prep: pos-emb index ----------------
__global__ void k_prep_idx(const float* __restrict__ nefi, int* __restrict__ idxws){
  int b = blockIdx.x, s = threadIdx.x;       // 1024 x 64
  int r = b*64 + s;
  float v = nefi[r];
  float mx = v;
  #pragma unroll
  for (int off = 32; off; off >>= 1) mx = fmaxf(mx, __shfl_xor(mx, off));
  idxws[r] = (v == -1.0f) ? 64 : (int)(floorf(v / mx) * 64.0f);
}

// ---------------- fused main kernel ----------------
// 128 rows/block, 1024 threads = 16 waves: rowg = w>>2 (32 rows = 2 row-tiles),
// colg = w&3 (96 cols = 6 col-tiles). act LDS [128][384] bf16 swizzled
// byte ^= (row&7)<<4. B tiles DMA-staged (global_load_lds, 2x24KB dbuf),
// counted per-wave vmcnt + raw barriers (2-phase pipeline, kc 8..79 continuous).
__device__ __forceinline__ short8 lds_rd(const char* lds, int row, int colElem){
  return *(const short8*)&lds[row*768 + ((colElem*2) ^ ((row & 7) << 4))];
}
__device__ __forceinline__ void lds_wr16(char* lds, int row, int col, unsigned short val){
  *(unsigned short*)&lds[row*768 + ((col*2) ^ ((row & 7) << 4))] = val;
}
__device__ __forceinline__ short8 bfrag(const unsigned short* wfrag, int tile, int lane){
  return *(const short8*)(wfrag + ((size_t)tile << 9) + (lane << 3));
}

// stage one k-step (24 tiles x 1KB) into LDS buffer. waves 0..7: 2 chunks,
// waves 8..15: 1 chunk. LDS dest = wave-uniform base (+lane*16 implicit).
__device__ __forceinline__ void stageB(char* dst, const unsigned short* wfrag,
                                       int kc, int w, int lane){
  const char* src = (const char*)wfrag + (size_t)kc * 24576;
  if (w < 8){
    const int c0 = 2*w;
    __builtin_amdgcn_global_load_lds(
      (const __attribute__((address_space(1))) unsigned int*)(src + c0*1024 + lane*16),
      (__attribute__((address_space(3))) unsigned int*)(dst + c0*1024), 16, 0, 0);
    __builtin_amdgcn_global_load_lds(
      (const __attribute__((address_space(1))) unsigned int*)(src + (c0+1)*1024 + lane*16),
      (__attribute__((address_space(3))) unsigned int*)(dst + (c0+1)*1024), 16, 0, 0);
  } else {
    const int c = 16 + (w - 8);
    __builtin_amdgcn_global_load_lds(
      (const __attribute__((address_space(1))) unsigned int*)(src + c*1024 + lane*16),
      (__attribute__((address_space(3))) unsigned int*)(dst + c*1024), 16, 0, 0);
  }
}

// 12 pipeline iterations; global pipeline index j = JB..JB+11 (kc = 8+j).
#define GEMM12(ACC, JB) do {                                                        \
  _Pragma("unroll")                                                                 \
  for (int jj = 0; jj < 12; ++jj){                                                  \
    const int j = (JB) + jj;                                                        \
    if (j < 71) stageB(lds + BOFF + (((j+1)&1)*24576), wfrag, 8 + j + 1, w, lane);  \
    if (j < 71){ if (w < 8) { WAITVM(2); } else { WAITVM(1); } } else { WAITVM(0); }\
    __builtin_amdgcn_s_barrier();                                                   \
    __builtin_amdgcn_sched_barrier(0);                                              \
    {                                                                               \
      const char* bb = lds + BOFF + ((j&1)*24576);                                  \
      const int ce = jj*32 + hi*8;                                                  \
      short8 a0 = lds_rd(lds, mrow + m,      ce);                                   \
      short8 a1 = lds_rd(lds, mrow + 16 + m, ce);                                   \
      _Pragma("unroll")                                                             \
      for (int t = 0; t < 6; ++t){                                                  \
        short8 bf = *(const short8*)(bb + (nct + t)*1024 + lane*16);                \
        ACC[t]   = __builtin_amdgcn_mfma_f32_16x16x32_bf16(a0, bf, ACC[t],   0,0,0);\
        ACC[6+t] = __builtin_amdgcn_mfma_f32_16x16x32_bf16(a1, bf, ACC[6+t], 0,0,0);\
      }                                                                             \
    }                                                                               \
    __builtin_amdgcn_s_barrier();                                                   \
    __builtin_amdgcn_sched_barrier(0);                                              \
  }                                                                                 \
} while(0)

__global__ __launch_bounds__(1024, 4) void k_main(
    const float* __restrict__ lips, const float* __restrict__ lh,
    const float* __restrict__ rh,   const float* __restrict__ pose,
    const float* __restrict__ pos_emb,
    const unsigned short* __restrict__ wfrag,
    const int* __restrict__ idxws,
    float* __restrict__ out)
{
  __shared__ __align__(16) char lds[LDS_TOTAL];
  const int tid = threadIdx.x;
  const int w = tid >> 6, lane = tid & 63;
  const int hi = lane >> 4, m = lane & 15;
  const int mrow = (w >> 2) * 32;    // local row base (2 row-tiles of 16)
  const int nct  = (w & 3) * 6;      // col-tile base (6 tiles = 96 cols)
  const int blkRow = blockIdx.x * 128;

  // prologue: stage first GEMM k-step (kc=8) into buf0; lands during stage-1(br0)
  stageB(lds + BOFF, wfrag, 8, w, lane);

  f32x4 yacc[12];
  #pragma unroll
  for (int i = 0; i < 12; ++i) yacc[i] = f32x4{0.f,0.f,0.f,0.f};

  const float* xs[4]  = {lips, lh, rh, pose};
  const int Ks[4]  = {80, 42, 42, 20};
  const int kcs[4] = {3, 2, 2, 1};
  const int wbs[4] = {0, 3, 5, 7};

  #pragma unroll
  for (int br = 0; br < 4; ++br){
    const float* xp = xs[br];
    const int K = Ks[br], kc = kcs[br], wb = wbs[br];

    // A fragments + in-flight row sums (empty-frame mask, fp32-exact like ref)
    short8 af[2][3];
    float mk[2][4];
    #pragma unroll
    for (int rt = 0; rt < 2; ++rt){
      const float* rowp = xp + (size_t)(blkRow + mrow + rt*16 + m) * K;
      float s = 0.f;
      #pragma unroll
      for (int kt = 0; kt < 3; ++kt){
        if (kt < kc){
          short8 t8;
          #pragma unroll
          for (int j = 0; j < 8; ++j){
            int k = kt*32 + hi*8 + j;
            float v = (k < K) ? rowp[k] : 0.f;
            s += v;
            t8[j] = (short)f2bf(v);
          }
          af[rt][kt] = t8;
        }
      }
      s += __shfl_xor(s, 16);
      s += __shfl_xor(s, 32);        // full row-sum in all 4 hi-lanes
      #pragma unroll
      for (int r = 0; r < 4; ++r)
        mk[rt][r] = (__shfl(s, hi*4 + r) == 0.f) ? 0.f : 1.f;
    }

    // stage 1: h = relu(x @ W1) * mask -> act LDS (bf16); B direct from global
    {
      short8 bs[2][3];
      #pragma unroll
      for (int kt = 0; kt < 3; ++kt)
        if (kt < kc) bs[0][kt] = bfrag(wfrag, (wb+kt)*24 + nct, lane);
      #pragma unroll
      for (int t = 0; t < 6; ++t){
        if (t < 5){
          #pragma unroll
          for (int kt = 0; kt < 3; ++kt)
            if (kt < kc) bs[(t+1)&1][kt] = bfrag(wfrag, (wb+kt)*24 + nct + t + 1, lane);
        }
        #pragma unroll
        for (int rt = 0; rt < 2; ++rt){
          f32x4 acc = f32x4{0.f,0.f,0.f,0.f};
          #pragma unroll
          for (int kt = 0; kt < 3; ++kt)
            if (kt < kc)
              acc = __builtin_amdgcn_mfma_f32_16x16x32_bf16(af[rt][kt], bs[t&1][kt], acc, 0, 0, 0);
          #pragma unroll
          for (int r = 0; r < 4; ++r){
            const int lrow = mrow + rt*16 + hi*4 + r;
            lds_wr16(lds, lrow, (nct + t)*16 + m, f2bf(fmaxf(acc[r], 0.f) * mk[rt][r]));
          }
        }
      }
    }
    __syncthreads();        // act(h) visible

    // stage 2: Y += h @ (w_br * W2_br), pipeline j = br*12 .. br*12+11
    GEMM12(yacc, br*12);
    // trailing barrier of GEMM12 protects act for next branch's overwrite
  }

  // write Y (bf16) to act
  #pragma unroll
  for (int t = 0; t < 6; ++t)
    #pragma unroll
    for (int rt = 0; rt < 2; ++rt)
      #pragma unroll
      for (int r = 0; r < 4; ++r)
        lds_wr16(lds, mrow + rt*16 + hi*4 + r, (nct + t)*16 + m, f2bf(yacc[rt*6 + t][r]));
  __syncthreads();

  // stage 3: Z = Y @ fc1  (pipeline j = 48..59)
  f32x4 zacc[12];
  #pragma unroll
  for (int i = 0; i < 12; ++i) zacc[i] = f32x4{0.f,0.f,0.f,0.f};
  GEMM12(zacc, 48);
  #pragma unroll
  for (int t = 0; t < 6; ++t)
    #pragma unroll
    for (int rt = 0; rt < 2; ++rt)
      #pragma unroll
      for (int r = 0; r < 4; ++r)
        lds_wr16(lds, mrow + rt*16 + hi*4 + r, (nct + t)*16 + m, f2bf(fmaxf(zacc[rt*6 + t][r], 0.f)));
  __syncthreads();

  // stage 4: O = relu(Z) @ fc2  (pipeline j = 60..71)
  f32x4 oacc[12];
  #pragma unroll
  for (int i = 0; i < 12; ++i) oacc[i] = f32x4{0.f,0.f,0.f,0.f};
  GEMM12(oacc, 60);

  // epilogue: coalesced stores via f32 LDS staging (act region reused),
  // 4 row-groups of 32; pos_emb added in the coalesced pass.
  float* actF = (float*)lds;                   // 48 KB
  const int rowg = w >> 2;
  const int erow = tid >> 5, el = tid & 31;    // cooperative-store mapping
  #pragma unroll
  for (int g = 0; g < 4; ++g){
    if (rowg == g){
      #pragma unroll
      for (int t = 0; t < 6; ++t)
        #pragma unroll
        for (int rt = 0; rt < 2; ++rt)
          #pragma unroll
          for (int r = 0; r < 4; ++r)
            actF[(rt*16 + hi*4 + r)*384 + (nct + t)*16 + m] = oacc[rt*6 + t][r];
    }
    __syncthreads();
    {
      const int grow = blkRow + g*32 + erow;
      const int pid = idxws[grow];
      const float* pe = pos_emb + (size_t)pid * U;
      float* op = out + (size_t)grow * U;
      #pragma unroll
      for (int i = 0; i < 3; ++i){
        const int cc = el + i*32;              // f32x4 chunk 0..95
        f32x4 v = *(const f32x4*)(actF + erow*384 + cc*4);
        f32x4 p = *(const f32x4*)(pe + cc*4);
        *(f32x4*)(op + cc*4) = v + p;
      }
    }
    __syncthreads();
  }
}

extern "C" void kernel_launch(void* const* d_in, const int* in_sizes, int n_in,
                              void* d_out, int out_size, void* d_ws, size_t ws_size,
                              hipStream_t stream){
  const float* lips = (const float*)d_in[0];
  const float* lh   = (const float*)d_in[1];
  const float* rh   = (const float*)d_in[2];
  const float* pose = (const float*)d_in[3];
  const float* nefi = (const float*)d_in[4];
  const float* w1l  = (const float*)d_in[5];
  const float* w2l  = (const float*)d_in[6];
  const float* w1lh = (const float*)d_in[7];
  const float* w2lh = (const float*)d_in[8];
  const float* w1rh = (const float*)d_in[9];
  const float* w2rh = (const float*)d_in[10];
  const float* w1p  = (const float*)d_in[11];
  const float* w2p  = (const float*)d_in[12];
  const float* lw   = (const float*)d_in[13];
  const float* fc1  = (const float*)d_in[14];
  const float* fc2  = (const float*)d_in[15];
  const float* pemb = (const float*)d_in[16];
  float* out = (float*)d_out;
  char* ws = (char*)d_ws;
  unsigned short* wfrag = (unsigned short*)(ws + WFRAG_OFF);
  int* idxws = (int*)(ws + IDX_OFF);

  k_prep_w<<<80, 256, 0, stream>>>(w1l, w2l, w1lh, w2lh, w1rh, w2rh,
                                   w1p, w2p, fc1, fc2, lw, wfrag);
  k_prep_idx<<<1024, 64, 0, stream>>>(nefi, idxws);
  k_main<<<512, 1024, 0, stream>>>(lips, lh, rh, pose, pemb, wfrag, idxws, out);
}

// Round 6
// 404.853 us; speedup vs baseline: 1.2384x; 1.0310x over previous
//
#include <hip/hip_runtime.h>
#include <hip/hip_bf16.h>

typedef __attribute__((ext_vector_type(8))) short short8;
typedef __attribute__((ext_vector_type(4))) float f32x4;

#define NROWS 65536
#define U 384
#define NTILES 1920            // 80 k-chain steps * 24 col-tiles
#define WFRAG_OFF 0
#define IDX_OFF (NTILES*1024)  // 1,966,080 bytes

#define ACT_BYTES (128*768)    // 98304: [128][384] bf16, swizzled
#define BOFF ACT_BYTES         // two B k-step buffers of 24576 B
#define LDS_TOTAL (ACT_BYTES + 2*24576)   // 147456

#define WAITVM(N) asm volatile("s_waitcnt vmcnt(" #N ")" ::: "memory")

__device__ __forceinline__ unsigned short f2bf(float f){
  union { float f; unsigned u; } v; v.f = f;
  unsigned u = v.u;
  u += 0x7FFFu + ((u >> 16) & 1u);   // RNE
  return (unsigned short)(u >> 16);
}

// ---------------- prep: fragment-ordered bf16 weights (slab version) --------
// 240 blocks: kchain = bid/3, col-third = bid%3 (8 col-tiles = 128 cols each).
// softmax(lw) computed in-kernel.
// k-chain: [0,8)=W1 (lips 3, lh 2, rh 2, pose 1, zero-padded K),
// [8,56)=W2 per branch (x12, scaled by softmax w), [56,68)=fc1, [68,80)=fc2.
__global__ void k_prep_w(const float* __restrict__ w1l, const float* __restrict__ w2l,
                         const float* __restrict__ w1lh, const float* __restrict__ w2lh,
                         const float* __restrict__ w1rh, const float* __restrict__ w2rh,
                         const float* __restrict__ w1p,  const float* __restrict__ w2p,
                         const float* __restrict__ fc1,  const float* __restrict__ fc2,
                         const float* __restrict__ lw,   unsigned short* __restrict__ wfrag){
  __shared__ float slab[32*128];
  const int kchain = blockIdx.x / 3, third = blockIdx.x % 3, tid = threadIdx.x;
  // softmax of landmark weights (tiny, every thread)
  float m0 = fmaxf(fmaxf(lw[0], lw[1]), fmaxf(lw[2], lw[3]));
  float e0 = expf(lw[0]-m0), e1 = expf(lw[1]-m0), e2 = expf(lw[2]-m0), e3 = expf(lw[3]-m0);
  float es = e0+e1+e2+e3;
  float swv[4] = {e0/es, e1/es, e2/es, e3/es};

  const float* src; int K = 384; float scale = 1.f; int kt;
  if (kchain < 8){
    if      (kchain < 3){ src = w1l;  K = 80; kt = kchain;     }
    else if (kchain < 5){ src = w1lh; K = 42; kt = kchain - 3; }
    else if (kchain < 7){ src = w1rh; K = 42; kt = kchain - 5; }
    else                { src = w1p;  K = 20; kt = kchain - 7; }
  } else if (kchain < 56){
    int t = kchain - 8; int br = t / 12; kt = t % 12;
    src = (br==0) ? w2l : (br==1) ? w2lh : (br==2) ? w2rh : w2p;
    scale = swv[br];
  } else if (kchain < 68){ src = fc1; kt = kchain - 56; }
  else                   { src = fc2; kt = kchain - 68; }

  for (int idx = tid; idx < 32*128; idx += 256){
    int kk = idx >> 7, n0 = idx & 127;
    int k = kt*32 + kk;
    slab[idx] = (k < K) ? scale * src[(size_t)k*U + third*128 + n0] : 0.f;
  }
  __syncthreads();
  for (int p = tid; p < 8*64; p += 256){
    int nt0 = p >> 6, lane = p & 63;
    int hi = lane >> 4, m = lane & 15;
    short8 o;
    #pragma unroll
    for (int j = 0; j < 8; ++j)
      o[j] = (short)f2bf(slab[(hi*8 + j)*128 + nt0*16 + m]);
    int nt = third*8 + nt0;
    *(short8*)(wfrag + ((size_t)(kchain*24 + nt) << 9) + (lane << 3)) = o;
  }
}

// ---------------- prep: pos-emb index ----------------
// 256 blocks x 256 thr: 4 waves/block, one batch row per wave (64 frames).
__global__ void k_prep_idx(const float* __restrict__ nefi, int* __restrict__ idxws){
  int r = blockIdx.x*256 + threadIdx.x;       // = b*64 + s with wave-aligned rows
  float v = nefi[r];
  float mx = v;
  #pragma unroll
  for (int off = 32; off; off >>= 1) mx = fmaxf(mx, __shfl_xor(mx, off));
  idxws[r] = (v == -1.0f) ? 64 : (int)(floorf(v / mx) * 64.0f);
}

// ---------------- fused main kernel ----------------
// 128 rows/block, 1024 threads = 16 waves: rowg = w>>2 (32 rows = 2 row-tiles),
// colg = w&3 (96 cols = 6 col-tiles). act LDS [128][384] bf16 swizzled
// byte ^= (row&7)<<4. B tiles DMA-staged (global_load_lds, 2x24KB dbuf),
// counted per-wave vmcnt + raw barriers (2-phase pipeline, kc 8..79 continuous).
// launch_bounds(1024,2): 256-reg cap (LDS already limits to 1 block/CU, so
// occupancy is unchanged vs (1024,4) -- but no scratch spills).
__device__ __forceinline__ short8 lds_rd(const char* lds, int row, int colElem){
  return *(const short8*)&lds[row*768 + ((colElem*2) ^ ((row & 7) << 4))];
}
__device__ __forceinline__ void lds_wr16(char* lds, int row, int col, unsigned short val){
  *(unsigned short*)&lds[row*768 + ((col*2) ^ ((row & 7) << 4))] = val;
}
__device__ __forceinline__ short8 bfrag(const unsigned short* wfrag, int tile, int lane){
  return *(const short8*)(wfrag + ((size_t)tile << 9) + (lane << 3));
}

// stage one k-step (24 tiles x 1KB) into LDS buffer. waves 0..7: 2 chunks,
// waves 8..15: 1 chunk. LDS dest = wave-uniform base (+lane*16 implicit).
__device__ __forceinline__ void stageB(char* dst, const unsigned short* wfrag,
                                       int kc, int w, int lane){
  const char* src = (const char*)wfrag + (size_t)kc * 24576;
  if (w < 8){
    const int c0 = 2*w;
    __builtin_amdgcn_global_load_lds(
      (const __attribute__((address_space(1))) unsigned int*)(src + c0*1024 + lane*16),
      (__attribute__((address_space(3))) unsigned int*)(dst + c0*1024), 16, 0, 0);
    __builtin_amdgcn_global_load_lds(
      (const __attribute__((address_space(1))) unsigned int*)(src + (c0+1)*1024 + lane*16),
      (__attribute__((address_space(3))) unsigned int*)(dst + (c0+1)*1024), 16, 0, 0);
  } else {
    const int c = 16 + (w - 8);
    __builtin_amdgcn_global_load_lds(
      (const __attribute__((address_space(1))) unsigned int*)(src + c*1024 + lane*16),
      (__attribute__((address_space(3))) unsigned int*)(dst + c*1024), 16, 0, 0);
  }
}

// 12 pipeline iterations; global pipeline index j = JB..JB+11 (kc = 8+j).
#define GEMM12(ACC, JB) do {                                                        \
  _Pragma("unroll")                                                                 \
  for (int jj = 0; jj < 12; ++jj){                                                  \
    const int j = (JB) + jj;                                                        \
    if (j < 71) stageB(lds + BOFF + (((j+1)&1)*24576), wfrag, 8 + j + 1, w, lane);  \
    if (j < 71){ if (w < 8) { WAITVM(2); } else { WAITVM(1); } } else { WAITVM(0); }\
    __builtin_amdgcn_s_barrier();                                                   \
    __builtin_amdgcn_sched_barrier(0);                                              \
    {                                                                               \
      const char* bb = lds + BOFF + ((j&1)*24576);                                  \
      const int ce = jj*32 + hi*8;                                                  \
      short8 a0 = lds_rd(lds, mrow + m,      ce);                                   \
      short8 a1 = lds_rd(lds, mrow + 16 + m, ce);                                   \
      _Pragma("unroll")                                                             \
      for (int t = 0; t < 6; ++t){                                                  \
        short8 bf = *(const short8*)(bb + (nct + t)*1024 + lane*16);                \
        ACC[t]   = __builtin_amdgcn_mfma_f32_16x16x32_bf16(a0, bf, ACC[t],   0,0,0);\
        ACC[6+t] = __builtin_amdgcn_mfma_f32_16x16x32_bf16(a1, bf, ACC[6+t], 0,0,0);\
      }                                                                             \
    }                                                                               \
    __builtin_amdgcn_s_barrier();                                                   \
    __builtin_amdgcn_sched_barrier(0);                                              \
  }                                                                                 \
} while(0)

__global__ __launch_bounds__(1024, 2) void k_main(
    const float* __restrict__ lips, const float* __restrict__ lh,
    const float* __restrict__ rh,   const float* __restrict__ pose,
    const float* __restrict__ pos_emb,
    const unsigned short* __restrict__ wfrag,
    const int* __restrict__ idxws,
    float* __restrict__ out)
{
  __shared__ __align__(16) char lds[LDS_TOTAL];
  const int tid = threadIdx.x;
  const int w = tid >> 6, lane = tid & 63;
  const int hi = lane >> 4, m = lane & 15;
  const int mrow = (w >> 2) * 32;    // local row base (2 row-tiles of 16)
  const int nct  = (w & 3) * 6;      // col-tile base (6 tiles = 96 cols)
  const int blkRow = blockIdx.x * 128;

  // prologue: stage first GEMM k-step (kc=8) into buf0; lands during stage-1(br0)
  stageB(lds + BOFF, wfrag, 8, w, lane);

  f32x4 yacc[12];
  #pragma unroll
  for (int i = 0; i < 12; ++i) yacc[i] = f32x4{0.f,0.f,0.f,0.f};

  const float* xs[4]  = {lips, lh, rh, pose};
  const int Ks[4]  = {80, 42, 42, 20};
  const int kcs[4] = {3, 2, 2, 1};
  const int wbs[4] = {0, 3, 5, 7};

  #pragma unroll
  for (int br = 0; br < 4; ++br){
    const float* xp = xs[br];
    const int K = Ks[br], kc = kcs[br], wb = wbs[br];

    // A fragments + in-flight row sums (empty-frame mask, fp32-exact like ref)
    short8 af[2][3];
    float mk[2][4];
    #pragma unroll
    for (int rt = 0; rt < 2; ++rt){
      const float* rowp = xp + (size_t)(blkRow + mrow + rt*16 + m) * K;
      float s = 0.f;
      #pragma unroll
      for (int kt = 0; kt < 3; ++kt){
        if (kt < kc){
          short8 t8;
          #pragma unroll
          for (int j = 0; j < 8; ++j){
            int k = kt*32 + hi*8 + j;
            float v = (k < K) ? rowp[k] : 0.f;
            s += v;
            t8[j] = (short)f2bf(v);
          }
          af[rt][kt] = t8;
        }
      }
      s += __shfl_xor(s, 16);
      s += __shfl_xor(s, 32);        // full row-sum in all 4 hi-lanes
      #pragma unroll
      for (int r = 0; r < 4; ++r)
        mk[rt][r] = (__shfl(s, hi*4 + r) == 0.f) ? 0.f : 1.f;
    }

    // stage 1: h = relu(x @ W1) * mask -> act LDS (bf16); B direct from global
    {
      short8 bs[2][3];
      #pragma unroll
      for (int kt = 0; kt < 3; ++kt)
        if (kt < kc) bs[0][kt] = bfrag(wfrag, (wb+kt)*24 + nct, lane);
      #pragma unroll
      for (int t = 0; t < 6; ++t){
        if (t < 5){
          #pragma unroll
          for (int kt = 0; kt < 3; ++kt)
            if (kt < kc) bs[(t+1)&1][kt] = bfrag(wfrag, (wb+kt)*24 + nct + t + 1, lane);
        }
        #pragma unroll
        for (int rt = 0; rt < 2; ++rt){
          f32x4 acc = f32x4{0.f,0.f,0.f,0.f};
          #pragma unroll
          for (int kt = 0; kt < 3; ++kt)
            if (kt < kc)
              acc = __builtin_amdgcn_mfma_f32_16x16x32_bf16(af[rt][kt], bs[t&1][kt], acc, 0, 0, 0);
          #pragma unroll
          for (int r = 0; r < 4; ++r){
            const int lrow = mrow + rt*16 + hi*4 + r;
            lds_wr16(lds, lrow, (nct + t)*16 + m, f2bf(fmaxf(acc[r], 0.f) * mk[rt][r]));
          }
        }
      }
    }
    __syncthreads();        // act(h) visible

    // stage 2: Y += h @ (w_br * W2_br), pipeline j = br*12 .. br*12+11
    GEMM12(yacc, br*12);
    // trailing barrier of GEMM12 protects act for next branch's overwrite
  }

  // write Y (bf16) to act
  #pragma unroll
  for (int t = 0; t < 6; ++t)
    #pragma unroll
    for (int rt = 0; rt < 2; ++rt)
      #pragma unroll
      for (int r = 0; r < 4; ++r)
        lds_wr16(lds, mrow + rt*16 + hi*4 + r, (nct + t)*16 + m, f2bf(yacc[rt*6 + t][r]));
  __syncthreads();

  // stage 3: Z = Y @ fc1  (pipeline j = 48..59)
  f32x4 zacc[12];
  #pragma unroll
  for (int i = 0; i < 12; ++i) zacc[i] = f32x4{0.f,0.f,0.f,0.f};
  GEMM12(zacc, 48);
  #pragma unroll
  for (int t = 0; t < 6; ++t)
    #pragma unroll
    for (int rt = 0; rt < 2; ++rt)
      #pragma unroll
      for (int r = 0; r < 4; ++r)
        lds_wr16(lds, mrow + rt*16 + hi*4 + r, (nct + t)*16 + m, f2bf(fmaxf(zacc[rt*6 + t][r], 0.f)));
  __syncthreads();

  // stage 4: O = relu(Z) @ fc2  (pipeline j = 60..71)
  f32x4 oacc[12];
  #pragma unroll
  for (int i = 0; i < 12; ++i) oacc[i] = f32x4{0.f,0.f,0.f,0.f};
  GEMM12(oacc, 60);

  // epilogue: coalesced stores via f32 LDS staging (act region reused),
  // 4 row-groups of 32; pos_emb added in the coalesced pass.
  float* actF = (float*)lds;                   // 48 KB
  const int rowg = w >> 2;
  const int erow = tid >> 5, el = tid & 31;    // cooperative-store mapping
  #pragma unroll
  for (int g = 0; g < 4; ++g){
    if (rowg == g){
      #pragma unroll
      for (int t = 0; t < 6; ++t)
        #pragma unroll
        for (int rt = 0; rt < 2; ++rt)
          #pragma unroll
          for (int r = 0; r < 4; ++r)
            actF[(rt*16 + hi*4 + r)*384 + (nct + t)*16 + m] = oacc[rt*6 + t][r];
    }
    __syncthreads();
    {
      const int grow = blkRow + g*32 + erow;
      const int pid = idxws[grow];
      const float* pe = pos_emb + (size_t)pid * U;
      float* op = out + (size_t)grow * U;
      #pragma unroll
      for (int i = 0; i < 3; ++i){
        const int cc = el + i*32;              // f32x4 chunk 0..95
        f32x4 v = *(const f32x4*)(actF + erow*384 + cc*4);
        f32x4 p = *(const f32x4*)(pe + cc*4);
        *(f32x4*)(op + cc*4) = v + p;
      }
    }
    __syncthreads();
  }
}

extern "C" void kernel_launch(void* const* d_in, const int* in_sizes, int n_in,
                              void* d_out, int out_size, void* d_ws, size_t ws_size,
                              hipStream_t stream){
  const float* lips = (const float*)d_in[0];
  const float* lh   = (const float*)d_in[1];
  const float* rh   = (const float*)d_in[2];
  const float* pose = (const float*)d_in[3];
  const float* nefi = (const float*)d_in[4];
  const float* w1l  = (const float*)d_in[5];
  const float* w2l  = (const float*)d_in[6];
  const float* w1lh = (const float*)d_in[7];
  const float* w2lh = (const float*)d_in[8];
  const float* w1rh = (const float*)d_in[9];
  const float* w2rh = (const float*)d_in[10];
  const float* w1p  = (const float*)d_in[11];
  const float* w2p  = (const float*)d_in[12];
  const float* lw   = (const float*)d_in[13];
  const float* fc1  = (const float*)d_in[14];
  const float* fc2  = (const float*)d_in[15];
  const float* pemb = (const float*)d_in[16];
  float* out = (float*)d_out;
  char* ws = (char*)d_ws;
  unsigned short* wfrag = (unsigned short*)(ws + WFRAG_OFF);
  int* idxws = (int*)(ws + IDX_OFF);

  k_prep_w<<<240, 256, 0, stream>>>(w1l, w2l, w1lh, w2lh, w1rh, w2rh,
                                    w1p, w2p, fc1, fc2, lw, wfrag);
  k_prep_idx<<<256, 256, 0, stream>>>(nefi, idxws);
  k_main<<<512, 1024, 0, stream>>>(lips, lh, rh, pose, pemb, wfrag, idxws, out);
}

// Round 8
// 391.945 us; speedup vs baseline: 1.2792x; 1.0329x over previous
//
#include <hip/hip_runtime.h>
#include <hip/hip_bf16.h>

typedef __attribute__((ext_vector_type(8))) short short8;
typedef __attribute__((ext_vector_type(4))) float f32x4;

#define NROWS 65536
#define U 384
#define NTILES 1920            // 80 k-chain steps * 24 col-tiles
#define WFRAG_OFF 0
#define IDX_OFF (NTILES*1024)  // 1,966,080 bytes

#define ACT_BYTES (128*768)    // 98304: [128][384] bf16, swizzled
#define BOFF ACT_BYTES         // two B k-step buffers of 24576 B
#define LDS_TOTAL (ACT_BYTES + 2*24576)   // 147456

#define WAITVM(N) asm volatile("s_waitcnt vmcnt(" #N ")" ::: "memory")

__device__ __forceinline__ unsigned short f2bf(float f){
  union { float f; unsigned u; } v; v.f = f;
  unsigned u = v.u;
  u += 0x7FFFu + ((u >> 16) & 1u);   // RNE
  return (unsigned short)(u >> 16);
}

// ---------------- prep: weights (blocks 0..239) + pos-emb idx (blocks 240..495)
// weights: kchain = bid/3, col-third = bid%3 (8 col-tiles = 128 cols each).
// k-chain: [0,8)=W1 (lips 3, lh 2, rh 2, pose 1, zero-padded K),
// [8,56)=W2 per branch (x12, scaled by softmax w), [56,68)=fc1, [68,80)=fc2.
__global__ void k_prep(const float* __restrict__ w1l, const float* __restrict__ w2l,
                       const float* __restrict__ w1lh, const float* __restrict__ w2lh,
                       const float* __restrict__ w1rh, const float* __restrict__ w2rh,
                       const float* __restrict__ w1p,  const float* __restrict__ w2p,
                       const float* __restrict__ fc1,  const float* __restrict__ fc2,
                       const float* __restrict__ lw,   const float* __restrict__ nefi,
                       unsigned short* __restrict__ wfrag, int* __restrict__ idxws){
  if (blockIdx.x >= 240){
    // pos-emb index: one batch row per wave (64 frames), rows wave-aligned
    int r = (blockIdx.x - 240)*256 + threadIdx.x;
    float v = nefi[r];
    float mx = v;
    #pragma unroll
    for (int off = 32; off; off >>= 1) mx = fmaxf(mx, __shfl_xor(mx, off));
    idxws[r] = (v == -1.0f) ? 64 : (int)(floorf(v / mx) * 64.0f);
    return;
  }
  __shared__ float slab[32*128];
  const int kchain = blockIdx.x / 3, third = blockIdx.x % 3, tid = threadIdx.x;
  // softmax of landmark weights (tiny, every thread)
  float m0 = fmaxf(fmaxf(lw[0], lw[1]), fmaxf(lw[2], lw[3]));
  float e0 = expf(lw[0]-m0), e1 = expf(lw[1]-m0), e2 = expf(lw[2]-m0), e3 = expf(lw[3]-m0);
  float es = e0+e1+e2+e3;
  float swv[4] = {e0/es, e1/es, e2/es, e3/es};

  const float* src; int K = 384; float scale = 1.f; int kt;
  if (kchain < 8){
    if      (kchain < 3){ src = w1l;  K = 80; kt = kchain;     }
    else if (kchain < 5){ src = w1lh; K = 42; kt = kchain - 3; }
    else if (kchain < 7){ src = w1rh; K = 42; kt = kchain - 5; }
    else                { src = w1p;  K = 20; kt = kchain - 7; }
  } else if (kchain < 56){
    int t = kchain - 8; int br = t / 12; kt = t % 12;
    src = (br==0) ? w2l : (br==1) ? w2lh : (br==2) ? w2rh : w2p;
    scale = swv[br];
  } else if (kchain < 68){ src = fc1; kt = kchain - 56; }
  else                   { src = fc2; kt = kchain - 68; }

  for (int idx = tid; idx < 32*128; idx += 256){
    int kk = idx >> 7, n0 = idx & 127;
    int k = kt*32 + kk;
    slab[idx] = (k < K) ? scale * src[(size_t)k*U + third*128 + n0] : 0.f;
  }
  __syncthreads();
  for (int p = tid; p < 8*64; p += 256){
    int nt0 = p >> 6, lane = p & 63;
    int hi = lane >> 4, m = lane & 15;
    short8 o;
    #pragma unroll
    for (int j = 0; j < 8; ++j)
      o[j] = (short)f2bf(slab[(hi*8 + j)*128 + nt0*16 + m]);
    int nt = third*8 + nt0;
    *(short8*)(wfrag + ((size_t)(kchain*24 + nt) << 9) + (lane << 3)) = o;
  }
}

// ---------------- fused main kernel ----------------
// 128 rows/block, 1024 threads = 16 waves: rowg = w>>2 (32 rows = 2 row-tiles),
// colg = w&3 (96 cols = 6 col-tiles). act LDS [128][384] bf16 swizzled
// byte ^= (row&7)<<4. B tiles DMA-staged (global_load_lds, 2x24KB dbuf).
// SINGLE-barrier 2-phase pipeline (T3 minimum recipe):
//   stage(j+1) ; compute(j) ; vmcnt(0) ; barrier
// buf[(j+1)&1] was last read at iter j-1; end-of-(j-1) barrier orders reuse.
__device__ __forceinline__ short8 lds_rd(const char* lds, int row, int colElem){
  return *(const short8*)&lds[row*768 + ((colElem*2) ^ ((row & 7) << 4))];
}
__device__ __forceinline__ void lds_wr16(char* lds, int row, int col, unsigned short val){
  *(unsigned short*)&lds[row*768 + ((col*2) ^ ((row & 7) << 4))] = val;
}
__device__ __forceinline__ short8 bfrag(const unsigned short* wfrag, int tile, int lane){
  return *(const short8*)(wfrag + ((size_t)tile << 9) + (lane << 3));
}

// stage one k-step (24 tiles x 1KB) into LDS buffer. waves 0..7: 2 chunks,
// waves 8..15: 1 chunk. LDS dest = wave-uniform base (+lane*16 implicit).
__device__ __forceinline__ void stageB(char* dst, const unsigned short* wfrag,
                                       int kc, int w, int lane){
  const char* src = (const char*)wfrag + (size_t)kc * 24576;
  if (w < 8){
    const int c0 = 2*w;
    __builtin_amdgcn_global_load_lds(
      (const __attribute__((address_space(1))) unsigned int*)(src + c0*1024 + lane*16),
      (__attribute__((address_space(3))) unsigned int*)(dst + c0*1024), 16, 0, 0);
    __builtin_amdgcn_global_load_lds(
      (const __attribute__((address_space(1))) unsigned int*)(src + (c0+1)*1024 + lane*16),
      (__attribute__((address_space(3))) unsigned int*)(dst + (c0+1)*1024), 16, 0, 0);
  } else {
    const int c = 16 + (w - 8);
    __builtin_amdgcn_global_load_lds(
      (const __attribute__((address_space(1))) unsigned int*)(src + c*1024 + lane*16),
      (__attribute__((address_space(3))) unsigned int*)(dst + c*1024), 16, 0, 0);
  }
}

// 12 pipeline iterations; global pipeline index j = JB..JB+11 (kc = 8+j).
// One barrier per iteration; stage issued BEFORE compute so the vmcnt(0)
// drain has the whole compute phase of cover.
#define GEMM12(ACC, JB) do {                                                        \
  _Pragma("unroll")                                                                 \
  for (int jj = 0; jj < 12; ++jj){                                                  \
    const int j = (JB) + jj;                                                        \
    if (j < 71) stageB(lds + BOFF + (((j+1)&1)*24576), wfrag, 8 + j + 1, w, lane);  \
    {                                                                               \
      const char* bb = lds + BOFF + ((j&1)*24576);                                  \
      const int ce = jj*32 + hi*8;                                                  \
      short8 a0 = lds_rd(lds, mrow + m,      ce);                                   \
      short8 a1 = lds_rd(lds, mrow + 16 + m, ce);                                   \
      _Pragma("unroll")                                                             \
      for (int t = 0; t < 6; ++t){                                                  \
        short8 bf = *(const short8*)(bb + (nct + t)*1024 + lane*16);                \
        ACC[t]   = __builtin_amdgcn_mfma_f32_16x16x32_bf16(a0, bf, ACC[t],   0,0,0);\
        ACC[6+t] = __builtin_amdgcn_mfma_f32_16x16x32_bf16(a1, bf, ACC[6+t], 0,0,0);\
      }                                                                             \
    }                                                                               \
    WAITVM(0);                                                                      \
    __builtin_amdgcn_s_barrier();                                                   \
    __builtin_amdgcn_sched_barrier(0);                                              \
  }                                                                                 \
} while(0)

__global__ __launch_bounds__(1024, 2) void k_main(
    const float* __restrict__ lips, const float* __restrict__ lh,
    const float* __restrict__ rh,   const float* __restrict__ pose,
    const float* __restrict__ pos_emb,
    const unsigned short* __restrict__ wfrag,
    const int* __restrict__ idxws,
    float* __restrict__ out)
{
  __shared__ __align__(16) char lds[LDS_TOTAL];
  const int tid = threadIdx.x;
  const int w = tid >> 6, lane = tid & 63;
  const int hi = lane >> 4, m = lane & 15;
  const int mrow = (w >> 2) * 32;    // local row base (2 row-tiles of 16)
  const int nct  = (w & 3) * 6;      // col-tile base (6 tiles = 96 cols)
  const int blkRow = blockIdx.x * 128;

  // prologue: stage first GEMM k-step (kc=8) into buf0; lands during stage-1(br0)
  // (__syncthreads after stage-1 drains vmcnt fully before first GEMM12)
  stageB(lds + BOFF, wfrag, 8, w, lane);

  f32x4 yacc[12];
  #pragma unroll
  for (int i = 0; i < 12; ++i) yacc[i] = f32x4{0.f,0.f,0.f,0.f};

  const float* xs[4]  = {lips, lh, rh, pose};
  const int Ks[4]  = {80, 42, 42, 20};
  const int kcs[4] = {3, 2, 2, 1};
  const int wbs[4] = {0, 3, 5, 7};

  #pragma unroll
  for (int br = 0; br < 4; ++br){
    const float* xp = xs[br];
    const int K = Ks[br], kc = kcs[br], wb = wbs[br];

    // A fragments + in-flight row sums (empty-frame mask, fp32-exact like ref)
    short8 af[2][3];
    float mk[2][4];
    #pragma unroll
    for (int rt = 0; rt < 2; ++rt){
      const float* rowp = xp + (size_t)(blkRow + mrow + rt*16 + m) * K;
      float s = 0.f;
      #pragma unroll
      for (int kt = 0; kt < 3; ++kt){
        if (kt < kc){
          short8 t8;
          #pragma unroll
          for (int j = 0; j < 8; ++j){
            int k = kt*32 + hi*8 + j;
            float v = (k < K) ? rowp[k] : 0.f;
            s += v;
            t8[j] = (short)f2bf(v);
          }
          af[rt][kt] = t8;
        }
      }
      s += __shfl_xor(s, 16);
      s += __shfl_xor(s, 32);        // full row-sum in all 4 hi-lanes
      #pragma unroll
      for (int r = 0; r < 4; ++r)
        mk[rt][r] = (__shfl(s, hi*4 + r) == 0.f) ? 0.f : 1.f;
    }

    // stage 1: h = relu(x @ W1) * mask -> act LDS (bf16); B direct from global
    {
      short8 bs[2][3];
      #pragma unroll
      for (int kt = 0; kt < 3; ++kt)
        if (kt < kc) bs[0][kt] = bfrag(wfrag, (wb+kt)*24 + nct, lane);
      #pragma unroll
      for (int t = 0; t < 6; ++t){
        if (t < 5){
          #pragma unroll
          for (int kt = 0; kt < 3; ++kt)
            if (kt < kc) bs[(t+1)&1][kt] = bfrag(wfrag, (wb+kt)*24 + nct + t + 1, lane);
        }
        #pragma unroll
        for (int rt = 0; rt < 2; ++rt){
          f32x4 acc = f32x4{0.f,0.f,0.f,0.f};
          #pragma unroll
          for (int kt = 0; kt < 3; ++kt)
            if (kt < kc)
              acc = __builtin_amdgcn_mfma_f32_16x16x32_bf16(af[rt][kt], bs[t&1][kt], acc, 0, 0, 0);
          #pragma unroll
          for (int r = 0; r < 4; ++r){
            const int lrow = mrow + rt*16 + hi*4 + r;
            lds_wr16(lds, lrow, (nct + t)*16 + m, f2bf(fmaxf(acc[r], 0.f) * mk[rt][r]));
          }
        }
      }
    }
    __syncthreads();        // act(h) visible (+ full vmcnt drain -> buf0 ready)

    // stage 2: Y += h @ (w_br * W2_br), pipeline j = br*12 .. br*12+11
    GEMM12(yacc, br*12);
    // trailing barrier of GEMM12 protects act for next branch's overwrite
  }

  // write Y (bf16) to act
  #pragma unroll
  for (int t = 0; t < 6; ++t)
    #pragma unroll
    for (int rt = 0; rt < 2; ++rt)
      #pragma unroll
      for (int r = 0; r < 4; ++r)
        lds_wr16(lds, mrow + rt*16 + hi*4 + r, (nct + t)*16 + m, f2bf(yacc[rt*6 + t][r]));
  __syncthreads();

  // stage 3: Z = Y @ fc1  (pipeline j = 48..59)
  f32x4 zacc[12];
  #pragma unroll
  for (int i = 0; i < 12; ++i) zacc[i] = f32x4{0.f,0.f,0.f,0.f};
  GEMM12(zacc, 48);
  #pragma unroll
  for (int t = 0; t < 6; ++t)
    #pragma unroll
    for (int rt = 0; rt < 2; ++rt)
      #pragma unroll
      for (int r = 0; r < 4; ++r)
        lds_wr16(lds, mrow + rt*16 + hi*4 + r, (nct + t)*16 + m, f2bf(fmaxf(zacc[rt*6 + t][r], 0.f)));
  __syncthreads();

  // stage 4: O = relu(Z) @ fc2  (pipeline j = 60..71)
  f32x4 oacc[12];
  #pragma unroll
  for (int i = 0; i < 12; ++i) oacc[i] = f32x4{0.f,0.f,0.f,0.f};
  GEMM12(oacc, 60);

  // epilogue: coalesced stores via f32 LDS staging (act region reused),
  // 4 row-groups of 32; pos_emb added in the coalesced pass.
  float* actF = (float*)lds;                   // 48 KB
  const int rowg = w >> 2;
  const int erow = tid >> 5, el = tid & 31;    // cooperative-store mapping
  #pragma unroll
  for (int g = 0; g < 4; ++g){
    if (rowg == g){
      #pragma unroll
      for (int t = 0; t < 6; ++t)
        #pragma unroll
        for (int rt = 0; rt < 2; ++rt)
          #pragma unroll
          for (int r = 0; r < 4; ++r)
            actF[(rt*16 + hi*4 + r)*384 + (nct + t)*16 + m] = oacc[rt*6 + t][r];
    }
    __syncthreads();
    {
      const int grow = blkRow + g*32 + erow;
      const int pid = idxws[grow];
      const float* pe = pos_emb + (size_t)pid * U;
      float* op = out + (size_t)grow * U;
      #pragma unroll
      for (int i = 0; i < 3; ++i){
        const int cc = el + i*32;              // f32x4 chunk 0..95
        f32x4 v = *(const f32x4*)(actF + erow*384 + cc*4);
        f32x4 p = *(const f32x4*)(pe + cc*4);
        *(f32x4*)(op + cc*4) = v + p;
      }
    }
    __syncthreads();
  }
}

extern "C" void kernel_launch(void* const* d_in, const int* in_sizes, int n_in,
                              void* d_out, int out_size, void* d_ws, size_t ws_size,
                              hipStream_t stream){
  const float* lips = (const float*)d_in[0];
  const float* lh   = (const float*)d_in[1];
  const float* rh   = (const float*)d_in[2];
  const float* pose = (const float*)d_in[3];
  const float* nefi = (const float*)d_in[4];
  const float* w1l  = (const float*)d_in[5];
  const float* w2l  = (const float*)d_in[6];
  const float* w1lh = (const float*)d_in[7];
  const float* w2lh = (const float*)d_in[8];
  const float* w1rh = (const float*)d_in[9];
  const float* w2rh = (const float*)d_in[10];
  const float* w1p  = (const float*)d_in[11];
  const float* w2p  = (const float*)d_in[12];
  const float* lw   = (const float*)d_in[13];
  const float* fc1  = (const float*)d_in[14];
  const float* fc2  = (const float*)d_in[15];
  const float* pemb = (const float*)d_in[16];
  float* out = (float*)d_out;
  char* ws = (char*)d_ws;
  unsigned short* wfrag = (unsigned short*)(ws + WFRAG_OFF);
  int* idxws = (int*)(ws + IDX_OFF);

  k_prep<<<496, 256, 0, stream>>>(w1l, w2l, w1lh, w2lh, w1rh, w2rh,
                                  w1p, w2p, fc1, fc2, lw, nefi, wfrag, idxws);
  k_main<<<512, 1024, 0, stream>>>(lips, lh, rh, pose, pemb, wfrag, idxws, out);
}